// Round 2
// baseline (676.030 us; speedup 1.0000x reference)
//
#include <hip/hip_runtime.h>
#include <hip/hip_bf16.h>
#include <stdint.h>

#define N_NODES 20000
#define N_EDGES 640000
#define DIM 128

using bf16x8 = __attribute__((ext_vector_type(8))) short;
using f32x4  = __attribute__((ext_vector_type(4))) float;

static __device__ __forceinline__ unsigned short f2bf(float f) {
    union { float f; unsigned int u; } v; v.f = f;
    unsigned int r = v.u + 0x7FFFu + ((v.u >> 16) & 1u);
    return (unsigned short)(r >> 16);
}

// ---------------- prep: bf16 node table, transposed bf16 weights, zero counts ----------------
__global__ void prep_kernel(const float* __restrict__ node_feat,
                            const float* __restrict__ W1e, const float* __restrict__ W2e,
                            const float* __restrict__ W1n, const float* __restrict__ W2n,
                            unsigned short* __restrict__ node_bf,
                            unsigned short* __restrict__ Wt1e, unsigned short* __restrict__ Wt2e,
                            unsigned short* __restrict__ Wt1n, unsigned short* __restrict__ Wt2n,
                            int* __restrict__ counts) {
    int tid = blockIdx.x * blockDim.x + threadIdx.x;
    int stride = gridDim.x * blockDim.x;
    // vectorized node conversion: 8 floats -> 8 bf16 per iter
    for (int i = tid; i < N_NODES * DIM / 8; i += stride) {
        const float* p = node_feat + (size_t)i * 8;
        float4 f0 = *(const float4*)p;
        float4 f1 = *(const float4*)(p + 4);
        bf16x8 a;
        a[0] = (short)f2bf(f0.x); a[1] = (short)f2bf(f0.y);
        a[2] = (short)f2bf(f0.z); a[3] = (short)f2bf(f0.w);
        a[4] = (short)f2bf(f1.x); a[5] = (short)f2bf(f1.y);
        a[6] = (short)f2bf(f1.z); a[7] = (short)f2bf(f1.w);
        *(bf16x8*)(node_bf + (size_t)i * 8) = a;
    }
    // Wt[n][k] = W[k][n]
    for (int i = tid; i < DIM * 384; i += stride) { int n = i / 384, k = i % 384; Wt1e[i] = f2bf(W1e[k * DIM + n]); }
    for (int i = tid; i < DIM * DIM; i += stride) { int n = i / DIM, k = i % DIM; Wt2e[i] = f2bf(W2e[k * DIM + n]); }
    for (int i = tid; i < DIM * 256; i += stride) { int n = i / 256, k = i % 256; Wt1n[i] = f2bf(W1n[k * DIM + n]); }
    for (int i = tid; i < DIM * DIM; i += stride) { int n = i / DIM, k = i % DIM; Wt2n[i] = f2bf(W2n[k * DIM + n]); }
    for (int i = tid; i < N_NODES; i += stride) counts[i] = 0;
}

// ---------------- CSR build ----------------
__global__ void count_kernel(const int* __restrict__ eidx, int* __restrict__ counts) {
    int e = blockIdx.x * blockDim.x + threadIdx.x;
    if (e < N_EDGES) atomicAdd(&counts[eidx[N_EDGES + e]], 1);
}

// chunked scan: 1024 threads x 20 elements, shfl wave-scan, 2 barriers
__global__ void scan_kernel(const int* __restrict__ counts, int* __restrict__ offsets,
                            int* __restrict__ cursor) {
    __shared__ int wsum[16];
    const int CH = 20;  // 1024*20 = 20480 >= 20000
    int tid = threadIdx.x;
    int lane = tid & 63, wid = tid >> 6;
    int base = tid * CH;
    int s = 0;
    #pragma unroll
    for (int j = 0; j < CH; ++j) { int i = base + j; s += (i < N_NODES) ? counts[i] : 0; }
    int chunk = s;
    #pragma unroll
    for (int off = 1; off < 64; off <<= 1) { int t = __shfl_up(s, off, 64); if (lane >= off) s += t; }
    if (lane == 63) wsum[wid] = s;
    __syncthreads();
    if (tid == 0) {
        int run = 0;
        for (int w = 0; w < 16; ++w) { int t = wsum[w]; wsum[w] = run; run += t; }
    }
    __syncthreads();
    int run = wsum[wid] + s - chunk;  // exclusive prefix for this thread's chunk
    for (int j = 0; j < CH; ++j) {
        int i = base + j;
        if (i < N_NODES) { offsets[i] = run; cursor[i] = run; run += counts[i]; }
    }
}

__global__ void scatter_kernel(const int* __restrict__ eidx, int* __restrict__ cursor,
                               int* __restrict__ elist) {
    int e = blockIdx.x * blockDim.x + threadIdx.x;
    if (e < N_EDGES) {
        int p = atomicAdd(&cursor[eidx[N_EDGES + e]], 1);
        elist[p] = e;
    }
}

// ---------------- edge MLP ----------------
// block = 256 threads = 4 waves; wave owns 32 rows (2 row-tiles of 16); block = 128 edges.
// Per-wave private LDS slice (8448 B): bf16 h staging (32x128, XOR-swizzled) then f32
// output re-layout (16 rows x 132-float padded stride) for coalesced residual+store.
#define SLICE_B 8448
__launch_bounds__(256, 4)
__global__ void edge_kernel(const float* __restrict__ edge_feat,
                            const int* __restrict__ eidx,
                            const unsigned short* __restrict__ node_bf,
                            const unsigned short* __restrict__ Wt1e,
                            const unsigned short* __restrict__ Wt2e,
                            const float* __restrict__ b1e,
                            const float* __restrict__ b2e,
                            float* __restrict__ out_edge) {
    __shared__ char lds[4][SLICE_B];   // 33792 B/block
    const int tid = threadIdx.x;
    const int wv = tid >> 6;
    const int l = tid & 63;
    const int lr = l & 15;
    const int kg = l >> 4;
    char* slice = lds[wv];

    const int eBase = blockIdx.x * 128;
    const int wBase = eBase + wv * 32;

    int e[2], se[2], de[2];
    #pragma unroll
    for (int rt = 0; rt < 2; ++rt) {
        e[rt] = wBase + rt * 16 + lr;
        se[rt] = eidx[e[rt]];
        de[rt] = eidx[N_EDGES + e[rt]];
    }

    f32x4 acc[2][8];
    #pragma unroll
    for (int rt = 0; rt < 2; ++rt)
        #pragma unroll
        for (int t = 0; t < 8; ++t) acc[rt][t] = (f32x4){0.f, 0.f, 0.f, 0.f};

    // GEMM1: K = 384 (12 steps of 32)
    #pragma unroll
    for (int s = 0; s < 12; ++s) {
        const int kk = s * 32 + kg * 8;
        bf16x8 A[2];
        if (s < 4) {
            #pragma unroll
            for (int rt = 0; rt < 2; ++rt) {
                const float* p = edge_feat + (long)e[rt] * DIM + kk;
                float4 f0 = *(const float4*)p;
                float4 f1 = *(const float4*)(p + 4);
                bf16x8 a;
                a[0] = (short)f2bf(f0.x); a[1] = (short)f2bf(f0.y);
                a[2] = (short)f2bf(f0.z); a[3] = (short)f2bf(f0.w);
                a[4] = (short)f2bf(f1.x); a[5] = (short)f2bf(f1.y);
                a[6] = (short)f2bf(f1.z); a[7] = (short)f2bf(f1.w);
                A[rt] = a;
            }
        } else if (s < 8) {
            #pragma unroll
            for (int rt = 0; rt < 2; ++rt)
                A[rt] = *(const bf16x8*)(node_bf + (long)se[rt] * DIM + (kk - 128));
        } else {
            #pragma unroll
            for (int rt = 0; rt < 2; ++rt)
                A[rt] = *(const bf16x8*)(node_bf + (long)de[rt] * DIM + (kk - 256));
        }
        #pragma unroll
        for (int t = 0; t < 8; ++t) {
            bf16x8 B = *(const bf16x8*)(Wt1e + (t * 16 + lr) * 384 + kk);
            #pragma unroll
            for (int rt = 0; rt < 2; ++rt)
                acc[rt][t] = __builtin_amdgcn_mfma_f32_16x16x32_bf16(A[rt], B, acc[rt][t], 0, 0, 0);
        }
    }

    // epilogue 1: bias + silu -> bf16 h in own slice (XOR swizzle)
    #pragma unroll
    for (int rt = 0; rt < 2; ++rt) {
        #pragma unroll
        for (int t = 0; t < 8; ++t) {
            float b1 = b1e[t * 16 + lr];
            int col = t * 16 + lr;
            #pragma unroll
            for (int r = 0; r < 4; ++r) {
                int row = rt * 16 + kg * 4 + r;   // 0..31
                float x = acc[rt][t][r] + b1;
                float h = x / (1.0f + __expf(-x));
                int byte = (row * 256 + col * 2) ^ ((row & 7) << 4);
                *(unsigned short*)(slice + byte) = f2bf(h);
            }
        }
    }
    __syncthreads();

    // GEMM2: K = 128 (4 steps)
    f32x4 acc2[2][8];
    #pragma unroll
    for (int rt = 0; rt < 2; ++rt)
        #pragma unroll
        for (int t = 0; t < 8; ++t) acc2[rt][t] = (f32x4){0.f, 0.f, 0.f, 0.f};

    #pragma unroll
    for (int s = 0; s < 4; ++s) {
        const int kk = s * 32 + kg * 8;
        bf16x8 A[2];
        #pragma unroll
        for (int rt = 0; rt < 2; ++rt) {
            int row = rt * 16 + lr;
            int byte = (row * 256 + kk * 2) ^ ((row & 7) << 4);
            A[rt] = *(const bf16x8*)(slice + byte);
        }
        #pragma unroll
        for (int t = 0; t < 8; ++t) {
            bf16x8 B = *(const bf16x8*)(Wt2e + (t * 16 + lr) * DIM + kk);
            #pragma unroll
            for (int rt = 0; rt < 2; ++rt)
                acc2[rt][t] = __builtin_amdgcn_mfma_f32_16x16x32_bf16(A[rt], B, acc2[rt][t], 0, 0, 0);
        }
    }
    __syncthreads();

    // epilogue 2: per rt, stage f32 tile in own slice (padded stride 132, col^(row&12)
    // swizzle), then coalesced float4 residual-add + store.
    #pragma unroll
    for (int rt = 0; rt < 2; ++rt) {
        float* sf = (float*)slice;
        #pragma unroll
        for (int t = 0; t < 8; ++t) {
            float b2 = b2e[t * 16 + lr];
            int col = t * 16 + lr;
            #pragma unroll
            for (int r = 0; r < 4; ++r) {
                int row = kg * 4 + r;             // 0..15
                int colp = col ^ (row & 12);
                sf[row * 132 + colp] = acc2[rt][t][r] + b2;
            }
        }
        __syncthreads();
        #pragma unroll
        for (int rr = 0; rr < 8; ++rr) {
            int row = rr * 2 + (l >> 5);          // 0..15
            int c4 = (l & 31) * 4;
            int cswz = c4 ^ (row & 12);
            float4 v = *(const float4*)(sf + row * 132 + cswz);
            long gidx = (long)(wBase + rt * 16 + row) * DIM + c4;
            float4 rsd = *(const float4*)(edge_feat + gidx);
            v.x += rsd.x; v.y += rsd.y; v.z += rsd.z; v.w += rsd.w;
            *(float4*)(out_edge + gidx) = v;
        }
        __syncthreads();
    }
}

// ---------------- mean aggregation (CSR pull, unrolled x4 gathers) ----------------
__global__ void agg_kernel(const float* __restrict__ edge_out,
                           const int* __restrict__ offsets, const int* __restrict__ counts,
                           const int* __restrict__ elist,
                           unsigned short* __restrict__ agg_bf) {
    int n = blockIdx.x * 4 + (threadIdx.x >> 6);
    int l = threadIdx.x & 63;
    if (n >= N_NODES) return;
    int off = offsets[n], cnt = counts[n];
    float a0 = 0.f, a1 = 0.f;
    int i = 0;
    for (; i + 4 <= cnt; i += 4) {
        int e0 = elist[off + i], e1 = elist[off + i + 1];
        int e2 = elist[off + i + 2], e3 = elist[off + i + 3];
        float2 v0 = *(const float2*)(edge_out + (long)e0 * DIM + l * 2);
        float2 v1 = *(const float2*)(edge_out + (long)e1 * DIM + l * 2);
        float2 v2 = *(const float2*)(edge_out + (long)e2 * DIM + l * 2);
        float2 v3 = *(const float2*)(edge_out + (long)e3 * DIM + l * 2);
        a0 += v0.x + v1.x + v2.x + v3.x;
        a1 += v0.y + v1.y + v2.y + v3.y;
    }
    for (; i < cnt; ++i) {
        int e = elist[off + i];
        float2 v = *(const float2*)(edge_out + (long)e * DIM + l * 2);
        a0 += v.x; a1 += v.y;
    }
    float inv = 1.0f / fmaxf((float)cnt, 1.0f);
    agg_bf[n * DIM + l * 2] = f2bf(a0 * inv);
    agg_bf[n * DIM + l * 2 + 1] = f2bf(a1 * inv);
}

// ---------------- node MLP ----------------
__launch_bounds__(256, 4)
__global__ void node_kernel(const float* __restrict__ node_feat,
                            const unsigned short* __restrict__ node_bf,
                            const unsigned short* __restrict__ agg_bf,
                            const unsigned short* __restrict__ Wt1n,
                            const unsigned short* __restrict__ Wt2n,
                            const float* __restrict__ b1n,
                            const float* __restrict__ b2n,
                            float* __restrict__ out_node) {
    __shared__ char lds[4][SLICE_B];
    const int tid = threadIdx.x;
    const int wv = tid >> 6;
    const int l = tid & 63;
    const int lr = l & 15;
    const int kg = l >> 4;
    char* slice = lds[wv];

    const int nBase = blockIdx.x * 128;
    const int wBase = nBase + wv * 32;

    int rowc[2];
    #pragma unroll
    for (int rt = 0; rt < 2; ++rt) {
        int row = wBase + rt * 16 + lr;
        rowc[rt] = row < N_NODES ? row : N_NODES - 1;
    }

    f32x4 acc[2][8];
    #pragma unroll
    for (int rt = 0; rt < 2; ++rt)
        #pragma unroll
        for (int t = 0; t < 8; ++t) acc[rt][t] = (f32x4){0.f, 0.f, 0.f, 0.f};

    // GEMM1: K = 256 (8 steps)
    #pragma unroll
    for (int s = 0; s < 8; ++s) {
        const int kk = s * 32 + kg * 8;
        bf16x8 A[2];
        if (s < 4) {
            #pragma unroll
            for (int rt = 0; rt < 2; ++rt)
                A[rt] = *(const bf16x8*)(node_bf + (long)rowc[rt] * DIM + kk);
        } else {
            #pragma unroll
            for (int rt = 0; rt < 2; ++rt)
                A[rt] = *(const bf16x8*)(agg_bf + (long)rowc[rt] * DIM + (kk - 128));
        }
        #pragma unroll
        for (int t = 0; t < 8; ++t) {
            bf16x8 B = *(const bf16x8*)(Wt1n + (t * 16 + lr) * 256 + kk);
            #pragma unroll
            for (int rt = 0; rt < 2; ++rt)
                acc[rt][t] = __builtin_amdgcn_mfma_f32_16x16x32_bf16(A[rt], B, acc[rt][t], 0, 0, 0);
        }
    }

    #pragma unroll
    for (int rt = 0; rt < 2; ++rt) {
        #pragma unroll
        for (int t = 0; t < 8; ++t) {
            float b1 = b1n[t * 16 + lr];
            int col = t * 16 + lr;
            #pragma unroll
            for (int r = 0; r < 4; ++r) {
                int row = rt * 16 + kg * 4 + r;
                float x = acc[rt][t][r] + b1;
                float h = x / (1.0f + __expf(-x));
                int byte = (row * 256 + col * 2) ^ ((row & 7) << 4);
                *(unsigned short*)(slice + byte) = f2bf(h);
            }
        }
    }
    __syncthreads();

    f32x4 acc2[2][8];
    #pragma unroll
    for (int rt = 0; rt < 2; ++rt)
        #pragma unroll
        for (int t = 0; t < 8; ++t) acc2[rt][t] = (f32x4){0.f, 0.f, 0.f, 0.f};

    #pragma unroll
    for (int s = 0; s < 4; ++s) {
        const int kk = s * 32 + kg * 8;
        bf16x8 A[2];
        #pragma unroll
        for (int rt = 0; rt < 2; ++rt) {
            int row = rt * 16 + lr;
            int byte = (row * 256 + kk * 2) ^ ((row & 7) << 4);
            A[rt] = *(const bf16x8*)(slice + byte);
        }
        #pragma unroll
        for (int t = 0; t < 8; ++t) {
            bf16x8 B = *(const bf16x8*)(Wt2n + (t * 16 + lr) * DIM + kk);
            #pragma unroll
            for (int rt = 0; rt < 2; ++rt)
                acc2[rt][t] = __builtin_amdgcn_mfma_f32_16x16x32_bf16(A[rt], B, acc2[rt][t], 0, 0, 0);
        }
    }
    __syncthreads();

    #pragma unroll
    for (int rt = 0; rt < 2; ++rt) {
        float* sf = (float*)slice;
        #pragma unroll
        for (int t = 0; t < 8; ++t) {
            float b2 = b2n[t * 16 + lr];
            int col = t * 16 + lr;
            #pragma unroll
            for (int r = 0; r < 4; ++r) {
                int row = kg * 4 + r;
                int colp = col ^ (row & 12);
                sf[row * 132 + colp] = acc2[rt][t][r] + b2;
            }
        }
        __syncthreads();
        #pragma unroll
        for (int rr = 0; rr < 8; ++rr) {
            int row = rr * 2 + (l >> 5);
            int c4 = (l & 31) * 4;
            int cswz = c4 ^ (row & 12);
            float4 v = *(const float4*)(sf + row * 132 + cswz);
            int grow = wBase + rt * 16 + row;
            if (grow < N_NODES) {
                long gidx = (long)grow * DIM + c4;
                float4 rsd = *(const float4*)(node_feat + gidx);
                v.x += rsd.x; v.y += rsd.y; v.z += rsd.z; v.w += rsd.w;
                *(float4*)(out_node + gidx) = v;
            }
        }
        __syncthreads();
    }
}

extern "C" void kernel_launch(void* const* d_in, const int* in_sizes, int n_in,
                              void* d_out, int out_size, void* d_ws, size_t ws_size,
                              hipStream_t stream) {
    const float* node_feat = (const float*)d_in[0];
    const float* edge_feat = (const float*)d_in[1];
    const int*   eidx      = (const int*)d_in[2];
    const float* W1e = (const float*)d_in[3];
    const float* b1e = (const float*)d_in[4];
    const float* W2e = (const float*)d_in[5];
    const float* b2e = (const float*)d_in[6];
    const float* W1n = (const float*)d_in[7];
    const float* b1n = (const float*)d_in[8];
    const float* W2n = (const float*)d_in[9];
    const float* b2n = (const float*)d_in[10];

    char* ws = (char*)d_ws;
    size_t off = 0;
    auto alloc = [&](size_t bytes) {
        void* p = ws + off;
        off += (bytes + 255) & ~(size_t)255;
        return p;
    };
    unsigned short* node_bf = (unsigned short*)alloc((size_t)N_NODES * DIM * 2);
    unsigned short* agg_bf  = (unsigned short*)alloc((size_t)N_NODES * DIM * 2);
    unsigned short* Wt1e    = (unsigned short*)alloc((size_t)DIM * 384 * 2);
    unsigned short* Wt2e    = (unsigned short*)alloc((size_t)DIM * DIM * 2);
    unsigned short* Wt1n    = (unsigned short*)alloc((size_t)DIM * 256 * 2);
    unsigned short* Wt2n    = (unsigned short*)alloc((size_t)DIM * DIM * 2);
    int* counts  = (int*)alloc((size_t)N_NODES * 4);
    int* offsets = (int*)alloc((size_t)N_NODES * 4);
    int* cursor  = (int*)alloc((size_t)N_NODES * 4);
    int* elist   = (int*)alloc((size_t)N_EDGES * 4);

    float* out_node = (float*)d_out;
    float* out_edge = out_node + (size_t)N_NODES * DIM;

    prep_kernel<<<512, 256, 0, stream>>>(node_feat, W1e, W2e, W1n, W2n,
                                         node_bf, Wt1e, Wt2e, Wt1n, Wt2n, counts);
    count_kernel<<<(N_EDGES + 255) / 256, 256, 0, stream>>>(eidx, counts);
    scan_kernel<<<1, 1024, 0, stream>>>(counts, offsets, cursor);
    scatter_kernel<<<(N_EDGES + 255) / 256, 256, 0, stream>>>(eidx, cursor, elist);
    edge_kernel<<<N_EDGES / 128, 256, 0, stream>>>(edge_feat, eidx, node_bf, Wt1e, Wt2e,
                                                   b1e, b2e, out_edge);
    agg_kernel<<<(N_NODES + 3) / 4, 256, 0, stream>>>(out_edge, offsets, counts, elist, agg_bf);
    node_kernel<<<(N_NODES + 127) / 128, 256, 0, stream>>>(node_feat, node_bf, agg_bf,
                                                           Wt1n, Wt2n, b1n, b2n, out_node);
}

// Round 3
// 496.848 us; speedup vs baseline: 1.3606x; 1.3606x over previous
//
#include <hip/hip_runtime.h>
#include <hip/hip_bf16.h>
#include <stdint.h>

#define N_NODES 20000
#define N_EDGES 640000
#define DIM 128

using bf16x8 = __attribute__((ext_vector_type(8))) short;
using f32x4  = __attribute__((ext_vector_type(4))) float;

static __device__ __forceinline__ unsigned short f2bf(float f) {
    union { float f; unsigned int u; } v; v.f = f;
    unsigned int r = v.u + 0x7FFFu + ((v.u >> 16) & 1u);
    return (unsigned short)(r >> 16);
}

// ---------------- prep: bf16 node table, transposed bf16 weights, zero counts ----------------
__global__ void prep_kernel(const float* __restrict__ node_feat,
                            const float* __restrict__ W1e, const float* __restrict__ W2e,
                            const float* __restrict__ W1n, const float* __restrict__ W2n,
                            unsigned short* __restrict__ node_bf,
                            unsigned short* __restrict__ Wt1e, unsigned short* __restrict__ Wt2e,
                            unsigned short* __restrict__ Wt1n, unsigned short* __restrict__ Wt2n,
                            int* __restrict__ counts) {
    int tid = blockIdx.x * blockDim.x + threadIdx.x;
    int stride = gridDim.x * blockDim.x;
    for (int i = tid; i < N_NODES * DIM / 8; i += stride) {
        const float* p = node_feat + (size_t)i * 8;
        float4 f0 = *(const float4*)p;
        float4 f1 = *(const float4*)(p + 4);
        bf16x8 a;
        a[0] = (short)f2bf(f0.x); a[1] = (short)f2bf(f0.y);
        a[2] = (short)f2bf(f0.z); a[3] = (short)f2bf(f0.w);
        a[4] = (short)f2bf(f1.x); a[5] = (short)f2bf(f1.y);
        a[6] = (short)f2bf(f1.z); a[7] = (short)f2bf(f1.w);
        *(bf16x8*)(node_bf + (size_t)i * 8) = a;
    }
    // Wt[n][k] = W[k][n]
    for (int i = tid; i < DIM * 384; i += stride) { int n = i / 384, k = i % 384; Wt1e[i] = f2bf(W1e[k * DIM + n]); }
    for (int i = tid; i < DIM * DIM; i += stride) { int n = i / DIM, k = i % DIM; Wt2e[i] = f2bf(W2e[k * DIM + n]); }
    for (int i = tid; i < DIM * 256; i += stride) { int n = i / 256, k = i % 256; Wt1n[i] = f2bf(W1n[k * DIM + n]); }
    for (int i = tid; i < DIM * DIM; i += stride) { int n = i / DIM, k = i % DIM; Wt2n[i] = f2bf(W2n[k * DIM + n]); }
    for (int i = tid; i < N_NODES; i += stride) counts[i] = 0;
}

// ---------------- CSR build ----------------
__global__ void count_kernel(const int* __restrict__ eidx, int* __restrict__ counts) {
    int e = blockIdx.x * blockDim.x + threadIdx.x;
    if (e < N_EDGES) atomicAdd(&counts[eidx[N_EDGES + e]], 1);
}

__global__ void scan_kernel(const int* __restrict__ counts, int* __restrict__ offsets,
                            int* __restrict__ cursor) {
    __shared__ int wsum[16];
    const int CH = 20;
    int tid = threadIdx.x;
    int lane = tid & 63, wid = tid >> 6;
    int base = tid * CH;
    int s = 0;
    #pragma unroll
    for (int j = 0; j < CH; ++j) { int i = base + j; s += (i < N_NODES) ? counts[i] : 0; }
    int chunk = s;
    #pragma unroll
    for (int off = 1; off < 64; off <<= 1) { int t = __shfl_up(s, off, 64); if (lane >= off) s += t; }
    if (lane == 63) wsum[wid] = s;
    __syncthreads();
    if (tid == 0) {
        int run = 0;
        for (int w = 0; w < 16; ++w) { int t = wsum[w]; wsum[w] = run; run += t; }
    }
    __syncthreads();
    int run = wsum[wid] + s - chunk;
    for (int j = 0; j < CH; ++j) {
        int i = base + j;
        if (i < N_NODES) { offsets[i] = run; cursor[i] = run; run += counts[i]; }
    }
}

__global__ void scatter_kernel(const int* __restrict__ eidx, int* __restrict__ cursor,
                               int* __restrict__ elist) {
    int e = blockIdx.x * blockDim.x + threadIdx.x;
    if (e < N_EDGES) {
        int p = atomicAdd(&cursor[eidx[N_EDGES + e]], 1);
        elist[p] = e;
    }
}

// ---------------- B-tile staging: 128 rows x 32 k (bf16) = 8 KB via global_load_lds ----------------
// LDS layout: row-major 64 B/row, k-chunk slot rotated by (row>>1)&3 so the
// 16-row x 4-kg ds_read_b128 pattern is perfectly bank-balanced (2 lanes/bank).
// Linear LDS dest (global_load_lds constraint) + inverse-rotated global source.
static __device__ __forceinline__ void stage_b(const unsigned short* __restrict__ src,
                                               int stride, int kk, char* buf,
                                               int wv, int l) {
    #pragma unroll
    for (int c = 0; c < 2; ++c) {
        int call = wv * 2 + c;
        int row = call * 16 + (l >> 2);
        int j = l & 3;
        int jg = (j - ((row >> 1) & 3)) & 3;
        const unsigned short* g = src + (size_t)row * stride + kk + jg * 8;
        __builtin_amdgcn_global_load_lds(
            (const __attribute__((address_space(1))) unsigned int*)(const void*)g,
            (__attribute__((address_space(3))) unsigned int*)(void*)(buf + call * 1024),
            16, 0, 0);
    }
}

// ---------------- edge MLP ----------------
// block = 128 edges x 128 cols, 4 waves in 2x2 grid (wave = 64 rows x 64 cols).
// B tiles double-buffered in LDS; A prefetched in regs; h in shared swizzled LDS.
__launch_bounds__(256, 3)
__global__ void edge_kernel(const float* __restrict__ edge_feat,
                            const int* __restrict__ eidx,
                            const unsigned short* __restrict__ node_bf,
                            const unsigned short* __restrict__ Wt1e,
                            const unsigned short* __restrict__ Wt2e,
                            const float* __restrict__ b1e,
                            const float* __restrict__ b2e,
                            float* __restrict__ out_edge) {
    __shared__ char ldsB[2][8192];
    __shared__ char ldsH[32768];
    const int tid = threadIdx.x;
    const int wv = tid >> 6;
    const int l = tid & 63;
    const int lr = l & 15;
    const int kg = l >> 4;
    const int rBase = (wv >> 1) * 64;
    const int cBase = (wv & 1) * 64;
    const int eBase = blockIdx.x * 128;

    int e[4], se[4], de[4];
    #pragma unroll
    for (int rt = 0; rt < 4; ++rt) {
        e[rt] = eBase + rBase + rt * 16 + lr;
        se[rt] = eidx[e[rt]];
        de[rt] = eidx[N_EDGES + e[rt]];
    }

    float b1r[4], b2r[4];
    #pragma unroll
    for (int tt = 0; tt < 4; ++tt) {
        b1r[tt] = b1e[cBase + tt * 16 + lr];
        b2r[tt] = b2e[cBase + tt * 16 + lr];
    }

    auto fetchA = [&](int s, bf16x8* A) {
        if (s < 4) {
            int kk = s * 32 + kg * 8;
            #pragma unroll
            for (int rt = 0; rt < 4; ++rt) {
                const float* p = edge_feat + (long)e[rt] * DIM + kk;
                float4 f0 = *(const float4*)p;
                float4 f1 = *(const float4*)(p + 4);
                bf16x8 a;
                a[0] = (short)f2bf(f0.x); a[1] = (short)f2bf(f0.y);
                a[2] = (short)f2bf(f0.z); a[3] = (short)f2bf(f0.w);
                a[4] = (short)f2bf(f1.x); a[5] = (short)f2bf(f1.y);
                a[6] = (short)f2bf(f1.z); a[7] = (short)f2bf(f1.w);
                A[rt] = a;
            }
        } else if (s < 8) {
            int kk = (s - 4) * 32 + kg * 8;
            #pragma unroll
            for (int rt = 0; rt < 4; ++rt)
                A[rt] = *(const bf16x8*)(node_bf + (long)se[rt] * DIM + kk);
        } else {
            int kk = (s - 8) * 32 + kg * 8;
            #pragma unroll
            for (int rt = 0; rt < 4; ++rt)
                A[rt] = *(const bf16x8*)(node_bf + (long)de[rt] * DIM + kk);
        }
    };

    f32x4 acc[4][4];
    #pragma unroll
    for (int rt = 0; rt < 4; ++rt)
        #pragma unroll
        for (int tt = 0; tt < 4; ++tt) acc[rt][tt] = (f32x4){0.f, 0.f, 0.f, 0.f};

    bf16x8 Acur[4], Anext[4];
    fetchA(0, Acur);
    stage_b(Wt1e, 384, 0, ldsB[0], wv, l);
    __syncthreads();

    // GEMM1: K = 384, 12 staged steps; step 11 pre-stages Wt2e tile 0.
    #pragma unroll
    for (int s = 0; s < 12; ++s) {
        if (s < 11) stage_b(Wt1e, 384, (s + 1) * 32, ldsB[(s + 1) & 1], wv, l);
        else        stage_b(Wt2e, 128, 0, ldsB[0], wv, l);
        if (s < 11) fetchA(s + 1, Anext);
        #pragma unroll
        for (int tt = 0; tt < 4; ++tt) {
            int n = cBase + tt * 16 + lr;
            int slot = (kg + ((n >> 1) & 3)) & 3;
            bf16x8 B = *(const bf16x8*)(ldsB[s & 1] + n * 64 + slot * 16);
            #pragma unroll
            for (int rt = 0; rt < 4; ++rt)
                acc[rt][tt] = __builtin_amdgcn_mfma_f32_16x16x32_bf16(Acur[rt], B, acc[rt][tt], 0, 0, 0);
        }
        __syncthreads();
        #pragma unroll
        for (int rt = 0; rt < 4; ++rt) Acur[rt] = Anext[rt];
    }

    // epilogue 1: bias + silu -> bf16 h (shared, XOR-swizzled)
    #pragma unroll
    for (int rt = 0; rt < 4; ++rt) {
        #pragma unroll
        for (int tt = 0; tt < 4; ++tt) {
            int col = cBase + tt * 16 + lr;
            #pragma unroll
            for (int r = 0; r < 4; ++r) {
                int row = rBase + rt * 16 + kg * 4 + r;
                float x = acc[rt][tt][r] + b1r[tt];
                float h = x / (1.0f + __expf(-x));
                int byte = (row * 256 + col * 2) ^ ((row & 7) << 4);
                *(unsigned short*)(ldsH + byte) = f2bf(h);
            }
        }
    }
    __syncthreads();

    // GEMM2: K = 128, 4 staged steps
    f32x4 acc2[4][4];
    #pragma unroll
    for (int rt = 0; rt < 4; ++rt)
        #pragma unroll
        for (int tt = 0; tt < 4; ++tt) acc2[rt][tt] = (f32x4){0.f, 0.f, 0.f, 0.f};

    #pragma unroll
    for (int q = 0; q < 4; ++q) {
        if (q < 3) stage_b(Wt2e, 128, (q + 1) * 32, ldsB[(q + 1) & 1], wv, l);
        bf16x8 A2[4];
        #pragma unroll
        for (int rt = 0; rt < 4; ++rt) {
            int row = rBase + rt * 16 + lr;
            int byte = (row * 256 + (q * 32 + kg * 8) * 2) ^ ((row & 7) << 4);
            A2[rt] = *(const bf16x8*)(ldsH + byte);
        }
        #pragma unroll
        for (int tt = 0; tt < 4; ++tt) {
            int n = cBase + tt * 16 + lr;
            int slot = (kg + ((n >> 1) & 3)) & 3;
            bf16x8 B = *(const bf16x8*)(ldsB[q & 1] + n * 64 + slot * 16);
            #pragma unroll
            for (int rt = 0; rt < 4; ++rt)
                acc2[rt][tt] = __builtin_amdgcn_mfma_f32_16x16x32_bf16(A2[rt], B, acc2[rt][tt], 0, 0, 0);
        }
        __syncthreads();
    }

    // epilogue 2: stage f32 tile per wave (16 rows x 64 cols, stride 68),
    // then coalesced float4 residual-add + store.
    float* sf = (float*)(ldsH + wv * 4352);
    #pragma unroll
    for (int rt = 0; rt < 4; ++rt) {
        #pragma unroll
        for (int tt = 0; tt < 4; ++tt) {
            #pragma unroll
            for (int r = 0; r < 4; ++r)
                sf[(kg * 4 + r) * 68 + tt * 16 + lr] = acc2[rt][tt][r] + b2r[tt];
        }
        #pragma unroll
        for (int rr = 0; rr < 4; ++rr) {
            int row16 = rr * 4 + kg;
            int c4 = lr * 4;
            float4 v = *(const float4*)(sf + row16 * 68 + c4);
            long gidx = (long)(eBase + rBase + rt * 16 + row16) * DIM + cBase + c4;
            float4 rsd = *(const float4*)(edge_feat + gidx);
            v.x += rsd.x; v.y += rsd.y; v.z += rsd.z; v.w += rsd.w;
            *(float4*)(out_edge + gidx) = v;
        }
    }
}

// ---------------- mean aggregation (CSR pull, unrolled x4 gathers) ----------------
__global__ void agg_kernel(const float* __restrict__ edge_out,
                           const int* __restrict__ offsets, const int* __restrict__ counts,
                           const int* __restrict__ elist,
                           unsigned short* __restrict__ agg_bf) {
    int n = blockIdx.x * 4 + (threadIdx.x >> 6);
    int l = threadIdx.x & 63;
    if (n >= N_NODES) return;
    int off = offsets[n], cnt = counts[n];
    float a0 = 0.f, a1 = 0.f;
    int i = 0;
    for (; i + 4 <= cnt; i += 4) {
        int e0 = elist[off + i], e1 = elist[off + i + 1];
        int e2 = elist[off + i + 2], e3 = elist[off + i + 3];
        float2 v0 = *(const float2*)(edge_out + (long)e0 * DIM + l * 2);
        float2 v1 = *(const float2*)(edge_out + (long)e1 * DIM + l * 2);
        float2 v2 = *(const float2*)(edge_out + (long)e2 * DIM + l * 2);
        float2 v3 = *(const float2*)(edge_out + (long)e3 * DIM + l * 2);
        a0 += v0.x + v1.x + v2.x + v3.x;
        a1 += v0.y + v1.y + v2.y + v3.y;
    }
    for (; i < cnt; ++i) {
        int e = elist[off + i];
        float2 v = *(const float2*)(edge_out + (long)e * DIM + l * 2);
        a0 += v.x; a1 += v.y;
    }
    float inv = 1.0f / fmaxf((float)cnt, 1.0f);
    agg_bf[n * DIM + l * 2] = f2bf(a0 * inv);
    agg_bf[n * DIM + l * 2 + 1] = f2bf(a1 * inv);
}

// ---------------- node MLP (R2 structure, small fraction of runtime) ----------------
#define SLICE_B 8448
__launch_bounds__(256, 4)
__global__ void node_kernel(const float* __restrict__ node_feat,
                            const unsigned short* __restrict__ node_bf,
                            const unsigned short* __restrict__ agg_bf,
                            const unsigned short* __restrict__ Wt1n,
                            const unsigned short* __restrict__ Wt2n,
                            const float* __restrict__ b1n,
                            const float* __restrict__ b2n,
                            float* __restrict__ out_node) {
    __shared__ char lds[4][SLICE_B];
    const int tid = threadIdx.x;
    const int wv = tid >> 6;
    const int l = tid & 63;
    const int lr = l & 15;
    const int kg = l >> 4;
    char* slice = lds[wv];

    const int nBase = blockIdx.x * 128;
    const int wBase = nBase + wv * 32;

    int rowc[2];
    #pragma unroll
    for (int rt = 0; rt < 2; ++rt) {
        int row = wBase + rt * 16 + lr;
        rowc[rt] = row < N_NODES ? row : N_NODES - 1;
    }

    f32x4 acc[2][8];
    #pragma unroll
    for (int rt = 0; rt < 2; ++rt)
        #pragma unroll
        for (int t = 0; t < 8; ++t) acc[rt][t] = (f32x4){0.f, 0.f, 0.f, 0.f};

    #pragma unroll
    for (int s = 0; s < 8; ++s) {
        const int kk = s * 32 + kg * 8;
        bf16x8 A[2];
        if (s < 4) {
            #pragma unroll
            for (int rt = 0; rt < 2; ++rt)
                A[rt] = *(const bf16x8*)(node_bf + (long)rowc[rt] * DIM + kk);
        } else {
            #pragma unroll
            for (int rt = 0; rt < 2; ++rt)
                A[rt] = *(const bf16x8*)(agg_bf + (long)rowc[rt] * DIM + (kk - 128));
        }
        #pragma unroll
        for (int t = 0; t < 8; ++t) {
            bf16x8 B = *(const bf16x8*)(Wt1n + (t * 16 + lr) * 256 + kk);
            #pragma unroll
            for (int rt = 0; rt < 2; ++rt)
                acc[rt][t] = __builtin_amdgcn_mfma_f32_16x16x32_bf16(A[rt], B, acc[rt][t], 0, 0, 0);
        }
    }

    #pragma unroll
    for (int rt = 0; rt < 2; ++rt) {
        #pragma unroll
        for (int t = 0; t < 8; ++t) {
            float b1 = b1n[t * 16 + lr];
            int col = t * 16 + lr;
            #pragma unroll
            for (int r = 0; r < 4; ++r) {
                int row = rt * 16 + kg * 4 + r;
                float x = acc[rt][t][r] + b1;
                float h = x / (1.0f + __expf(-x));
                int byte = (row * 256 + col * 2) ^ ((row & 7) << 4);
                *(unsigned short*)(slice + byte) = f2bf(h);
            }
        }
    }
    __syncthreads();

    f32x4 acc2[2][8];
    #pragma unroll
    for (int rt = 0; rt < 2; ++rt)
        #pragma unroll
        for (int t = 0; t < 8; ++t) acc2[rt][t] = (f32x4){0.f, 0.f, 0.f, 0.f};

    #pragma unroll
    for (int s = 0; s < 4; ++s) {
        const int kk = s * 32 + kg * 8;
        bf16x8 A[2];
        #pragma unroll
        for (int rt = 0; rt < 2; ++rt) {
            int row = rt * 16 + lr;
            int byte = (row * 256 + kk * 2) ^ ((row & 7) << 4);
            A[rt] = *(const bf16x8*)(slice + byte);
        }
        #pragma unroll
        for (int t = 0; t < 8; ++t) {
            bf16x8 B = *(const bf16x8*)(Wt2n + (t * 16 + lr) * DIM + kk);
            #pragma unroll
            for (int rt = 0; rt < 2; ++rt)
                acc2[rt][t] = __builtin_amdgcn_mfma_f32_16x16x32_bf16(A[rt], B, acc2[rt][t], 0, 0, 0);
        }
    }
    __syncthreads();

    #pragma unroll
    for (int rt = 0; rt < 2; ++rt) {
        float* sf = (float*)slice;
        #pragma unroll
        for (int t = 0; t < 8; ++t) {
            float b2 = b2n[t * 16 + lr];
            int col = t * 16 + lr;
            #pragma unroll
            for (int r = 0; r < 4; ++r) {
                int row = kg * 4 + r;
                int colp = col ^ (row & 12);
                sf[row * 132 + colp] = acc2[rt][t][r] + b2;
            }
        }
        __syncthreads();
        #pragma unroll
        for (int rr = 0; rr < 8; ++rr) {
            int row = rr * 2 + (l >> 5);
            int c4 = (l & 31) * 4;
            int cswz = c4 ^ (row & 12);
            float4 v = *(const float4*)(sf + row * 132 + cswz);
            int grow = wBase + rt * 16 + row;
            if (grow < N_NODES) {
                long gidx = (long)grow * DIM + c4;
                float4 rsd = *(const float4*)(node_feat + gidx);
                v.x += rsd.x; v.y += rsd.y; v.z += rsd.z; v.w += rsd.w;
                *(float4*)(out_node + gidx) = v;
            }
        }
        __syncthreads();
    }
}

extern "C" void kernel_launch(void* const* d_in, const int* in_sizes, int n_in,
                              void* d_out, int out_size, void* d_ws, size_t ws_size,
                              hipStream_t stream) {
    const float* node_feat = (const float*)d_in[0];
    const float* edge_feat = (const float*)d_in[1];
    const int*   eidx      = (const int*)d_in[2];
    const float* W1e = (const float*)d_in[3];
    const float* b1e = (const float*)d_in[4];
    const float* W2e = (const float*)d_in[5];
    const float* b2e = (const float*)d_in[6];
    const float* W1n = (const float*)d_in[7];
    const float* b1n = (const float*)d_in[8];
    const float* W2n = (const float*)d_in[9];
    const float* b2n = (const float*)d_in[10];

    char* ws = (char*)d_ws;
    size_t off = 0;
    auto alloc = [&](size_t bytes) {
        void* p = ws + off;
        off += (bytes + 255) & ~(size_t)255;
        return p;
    };
    unsigned short* node_bf = (unsigned short*)alloc((size_t)N_NODES * DIM * 2);
    unsigned short* agg_bf  = (unsigned short*)alloc((size_t)N_NODES * DIM * 2);
    unsigned short* Wt1e    = (unsigned short*)alloc((size_t)DIM * 384 * 2);
    unsigned short* Wt2e    = (unsigned short*)alloc((size_t)DIM * DIM * 2);
    unsigned short* Wt1n    = (unsigned short*)alloc((size_t)DIM * 256 * 2);
    unsigned short* Wt2n    = (unsigned short*)alloc((size_t)DIM * DIM * 2);
    int* counts  = (int*)alloc((size_t)N_NODES * 4);
    int* offsets = (int*)alloc((size_t)N_NODES * 4);
    int* cursor  = (int*)alloc((size_t)N_NODES * 4);
    int* elist   = (int*)alloc((size_t)N_EDGES * 4);

    float* out_node = (float*)d_out;
    float* out_edge = out_node + (size_t)N_NODES * DIM;

    prep_kernel<<<512, 256, 0, stream>>>(node_feat, W1e, W2e, W1n, W2n,
                                         node_bf, Wt1e, Wt2e, Wt1n, Wt2n, counts);
    count_kernel<<<(N_EDGES + 255) / 256, 256, 0, stream>>>(eidx, counts);
    scan_kernel<<<1, 1024, 0, stream>>>(counts, offsets, cursor);
    scatter_kernel<<<(N_EDGES + 255) / 256, 256, 0, stream>>>(eidx, cursor, elist);
    edge_kernel<<<N_EDGES / 128, 256, 0, stream>>>(edge_feat, eidx, node_bf, Wt1e, Wt2e,
                                                   b1e, b2e, out_edge);
    agg_kernel<<<(N_NODES + 3) / 4, 256, 0, stream>>>(out_edge, offsets, counts, elist, agg_bf);
    node_kernel<<<(N_NODES + 127) / 128, 256, 0, stream>>>(node_feat, node_bf, agg_bf,
                                                           Wt1n, Wt2n, b1n, b2n, out_node);
}

// Round 4
// 489.703 us; speedup vs baseline: 1.3805x; 1.0146x over previous
//
#include <hip/hip_runtime.h>
#include <hip/hip_bf16.h>
#include <stdint.h>

#define N_NODES 20000
#define N_EDGES 640000
#define DIM 128

using bf16x8 = __attribute__((ext_vector_type(8))) short;
using f32x4  = __attribute__((ext_vector_type(4))) float;

static __device__ __forceinline__ unsigned short f2bf(float f) {
    union { float f; unsigned int u; } v; v.f = f;
    unsigned int r = v.u + 0x7FFFu + ((v.u >> 16) & 1u);
    return (unsigned short)(r >> 16);
}

// ---------------- prep: bf16 node table, transposed bf16 weights, zero counts+agg ----------------
__global__ void prep_kernel(const float* __restrict__ node_feat,
                            const float* __restrict__ W1e, const float* __restrict__ W2e,
                            const float* __restrict__ W1n, const float* __restrict__ W2n,
                            unsigned short* __restrict__ node_bf,
                            unsigned short* __restrict__ Wt1e, unsigned short* __restrict__ Wt2e,
                            unsigned short* __restrict__ Wt1n, unsigned short* __restrict__ Wt2n,
                            int* __restrict__ counts, float* __restrict__ aggf) {
    int tid = blockIdx.x * blockDim.x + threadIdx.x;
    int stride = gridDim.x * blockDim.x;
    for (int i = tid; i < N_NODES * DIM / 8; i += stride) {
        const float* p = node_feat + (size_t)i * 8;
        float4 f0 = *(const float4*)p;
        float4 f1 = *(const float4*)(p + 4);
        bf16x8 a;
        a[0] = (short)f2bf(f0.x); a[1] = (short)f2bf(f0.y);
        a[2] = (short)f2bf(f0.z); a[3] = (short)f2bf(f0.w);
        a[4] = (short)f2bf(f1.x); a[5] = (short)f2bf(f1.y);
        a[6] = (short)f2bf(f1.z); a[7] = (short)f2bf(f1.w);
        *(bf16x8*)(node_bf + (size_t)i * 8) = a;
    }
    // Wt[n][k] = W[k][n]
    for (int i = tid; i < DIM * 384; i += stride) { int n = i / 384, k = i % 384; Wt1e[i] = f2bf(W1e[k * DIM + n]); }
    for (int i = tid; i < DIM * DIM; i += stride) { int n = i / DIM, k = i % DIM; Wt2e[i] = f2bf(W2e[k * DIM + n]); }
    for (int i = tid; i < DIM * 256; i += stride) { int n = i / 256, k = i % 256; Wt1n[i] = f2bf(W1n[k * DIM + n]); }
    for (int i = tid; i < DIM * DIM; i += stride) { int n = i / DIM, k = i % DIM; Wt2n[i] = f2bf(W2n[k * DIM + n]); }
    for (int i = tid; i < N_NODES; i += stride) counts[i] = 0;
    float4 z = {0.f, 0.f, 0.f, 0.f};
    for (int i = tid; i < N_NODES * DIM / 4; i += stride) *(float4*)(aggf + (size_t)i * 4) = z;
}

// ---------------- CSR build ----------------
__global__ void count_kernel(const int* __restrict__ eidx, int* __restrict__ counts) {
    int e = blockIdx.x * blockDim.x + threadIdx.x;
    if (e < N_EDGES) atomicAdd(&counts[eidx[N_EDGES + e]], 1);
}

__global__ void scan_kernel(const int* __restrict__ counts, int* __restrict__ offsets,
                            int* __restrict__ cursor) {
    __shared__ int wsum[16];
    const int CH = 20;
    int tid = threadIdx.x;
    int lane = tid & 63, wid = tid >> 6;
    int base = tid * CH;
    int s = 0;
    #pragma unroll
    for (int j = 0; j < CH; ++j) { int i = base + j; s += (i < N_NODES) ? counts[i] : 0; }
    int chunk = s;
    #pragma unroll
    for (int off = 1; off < 64; off <<= 1) { int t = __shfl_up(s, off, 64); if (lane >= off) s += t; }
    if (lane == 63) wsum[wid] = s;
    __syncthreads();
    if (tid == 0) {
        int run = 0;
        for (int w = 0; w < 16; ++w) { int t = wsum[w]; wsum[w] = run; run += t; }
    }
    __syncthreads();
    int run = wsum[wid] + s - chunk;
    for (int j = 0; j < CH; ++j) {
        int i = base + j;
        if (i < N_NODES) { offsets[i] = run; cursor[i] = run; run += counts[i]; }
    }
}

__global__ void scatter_kernel(const int* __restrict__ eidx, int* __restrict__ cursor,
                               int* __restrict__ elist, int* __restrict__ dsts) {
    int e = blockIdx.x * blockDim.x + threadIdx.x;
    if (e < N_EDGES) {
        int d = eidx[N_EDGES + e];
        int p = atomicAdd(&cursor[d], 1);
        elist[p] = e;
        dsts[p] = d;
    }
}

// ---------------- edge MLP + fused aggregation ----------------
// Block = 128 edges (in dst-sorted elist order), 4 waves, wave = 32 rows x 128 cols.
// LDS: ldsB 48KB (Wt1e half / Wt2e, slot-XOR swizzled, staged via global_load_lds
// with pre-swizzled source) + 4x8KB wave-private h. 80KB total -> 2 blocks/CU.
// K-loops are barrier-free: A-fragments burst-prefetched per half into registers.
static __device__ __forceinline__ void glds16(const unsigned short* g, char* lds) {
    __builtin_amdgcn_global_load_lds(
        (const __attribute__((address_space(1))) unsigned int*)(const void*)g,
        (__attribute__((address_space(3))) unsigned int*)(void*)lds, 16, 0, 0);
}

__launch_bounds__(256, 2)
__global__ void edge_kernel(const float* __restrict__ edge_feat,
                            const int* __restrict__ eidx,
                            const int* __restrict__ elist,
                            const int* __restrict__ dsts,
                            const unsigned short* __restrict__ node_bf,
                            const unsigned short* __restrict__ Wt1e,
                            const unsigned short* __restrict__ Wt2e,
                            const float* __restrict__ b1e,
                            const float* __restrict__ b2e,
                            float* __restrict__ out_edge,
                            float* __restrict__ aggf) {
    __shared__ char ldsB[49152];
    __shared__ char ldsH[4][8192];
    const int tid = threadIdx.x;
    const int wv = tid >> 6;
    const int l = tid & 63;
    const int lr = l & 15;
    const int kg = l >> 4;
    char* hslice = ldsH[wv];

    // XCD-chunked swizzle: 5000 blocks = 8 x 625
    const int bs = (blockIdx.x & 7) * 625 + (blockIdx.x >> 3);
    const int eBase = bs * 128;

    // stage Wt1e half [128 n][192 k]: dest linear, source slot pre-XOR'd (rule 21)
    auto stage_w1 = [&](int half) {
        #pragma unroll
        for (int c = 0; c < 12; ++c) {
            int S = c * 256 + tid;
            int n = S / 24;
            int s = S - n * 24;
            glds16(Wt1e + n * 384 + half * 192 + ((s ^ (n & 7)) << 3), ldsB + S * 16);
        }
    };
    auto stage_w2 = [&]() {
        #pragma unroll
        for (int c = 0; c < 8; ++c) {
            int S = c * 256 + tid;
            int n = S >> 4;
            int s = S & 15;
            glds16(Wt2e + n * 128 + ((s ^ (n & 7)) << 3), ldsB + S * 16);
        }
    };

    int ep[2], sp[2], dp[2];
    #pragma unroll
    for (int rt = 0; rt < 2; ++rt) {
        int gi = eBase + wv * 32 + rt * 16 + lr;
        ep[rt] = elist[gi];
        sp[rt] = eidx[ep[rt]];
        dp[rt] = eidx[N_EDGES + ep[rt]];
    }

    stage_w1(0);

    // ---- A prefetch, half 0: steps 0..3 edge_feat (fp32->bf16), 4..5 node_bf[src]
    bf16x8 Ah[12];
    {
        float4 ef[4][2][2];
        #pragma unroll
        for (int st = 0; st < 4; ++st)
            #pragma unroll
            for (int rt = 0; rt < 2; ++rt) {
                const float* p = edge_feat + (long)ep[rt] * DIM + st * 32 + kg * 8;
                ef[st][rt][0] = *(const float4*)p;
                ef[st][rt][1] = *(const float4*)(p + 4);
            }
        #pragma unroll
        for (int st = 4; st < 6; ++st)
            #pragma unroll
            for (int rt = 0; rt < 2; ++rt)
                Ah[st * 2 + rt] = *(const bf16x8*)(node_bf + (long)sp[rt] * DIM + (st - 4) * 32 + kg * 8);
        #pragma unroll
        for (int st = 0; st < 4; ++st)
            #pragma unroll
            for (int rt = 0; rt < 2; ++rt) {
                bf16x8 a;
                a[0] = (short)f2bf(ef[st][rt][0].x); a[1] = (short)f2bf(ef[st][rt][0].y);
                a[2] = (short)f2bf(ef[st][rt][0].z); a[3] = (short)f2bf(ef[st][rt][0].w);
                a[4] = (short)f2bf(ef[st][rt][1].x); a[5] = (short)f2bf(ef[st][rt][1].y);
                a[6] = (short)f2bf(ef[st][rt][1].z); a[7] = (short)f2bf(ef[st][rt][1].w);
                Ah[st * 2 + rt] = a;
            }
    }

    float b1r[8], b2r[8];
    #pragma unroll
    for (int tt = 0; tt < 8; ++tt) {
        b1r[tt] = b1e[tt * 16 + lr];
        b2r[tt] = b2e[tt * 16 + lr];
    }

    f32x4 acc[2][8];
    #pragma unroll
    for (int rt = 0; rt < 2; ++rt)
        #pragma unroll
        for (int tt = 0; tt < 8; ++tt) acc[rt][tt] = (f32x4){0.f, 0.f, 0.f, 0.f};

    __syncthreads();   // half-0 staged

    // ---- GEMM1, half 0 (barrier-free)
    #pragma unroll
    for (int ls = 0; ls < 6; ++ls) {
        #pragma unroll
        for (int tt = 0; tt < 8; ++tt) {
            int n = tt * 16 + lr;
            bf16x8 B = *(const bf16x8*)(ldsB + n * 384 + (((ls * 4 + kg) ^ (n & 7)) << 4));
            #pragma unroll
            for (int rt = 0; rt < 2; ++rt)
                acc[rt][tt] = __builtin_amdgcn_mfma_f32_16x16x32_bf16(Ah[ls * 2 + rt], B, acc[rt][tt], 0, 0, 0);
        }
    }

    // ---- A prefetch, half 1: steps 6..7 node_bf[src] k=64.., 8..11 node_bf[dst]
    #pragma unroll
    for (int st = 6; st < 8; ++st)
        #pragma unroll
        for (int rt = 0; rt < 2; ++rt)
            Ah[(st - 6) * 2 + rt] = *(const bf16x8*)(node_bf + (long)sp[rt] * DIM + (st - 4) * 32 + kg * 8);
    #pragma unroll
    for (int st = 8; st < 12; ++st)
        #pragma unroll
        for (int rt = 0; rt < 2; ++rt)
            Ah[(st - 6) * 2 + rt] = *(const bf16x8*)(node_bf + (long)dp[rt] * DIM + (st - 8) * 32 + kg * 8);

    __syncthreads();   // all waves done reading half 0
    stage_w1(1);
    __syncthreads();   // half-1 staged

    // ---- GEMM1, half 1
    #pragma unroll
    for (int ls = 0; ls < 6; ++ls) {
        #pragma unroll
        for (int tt = 0; tt < 8; ++tt) {
            int n = tt * 16 + lr;
            bf16x8 B = *(const bf16x8*)(ldsB + n * 384 + (((ls * 4 + kg) ^ (n & 7)) << 4));
            #pragma unroll
            for (int rt = 0; rt < 2; ++rt)
                acc[rt][tt] = __builtin_amdgcn_mfma_f32_16x16x32_bf16(Ah[ls * 2 + rt], B, acc[rt][tt], 0, 0, 0);
        }
    }

    __syncthreads();   // all waves done reading half 1
    stage_w2();        // overlaps epilogue-1 below

    // ---- epilogue 1: bias + silu -> wave-private h (XOR swizzle)
    #pragma unroll
    for (int rt = 0; rt < 2; ++rt)
        #pragma unroll
        for (int tt = 0; tt < 8; ++tt) {
            int col = tt * 16 + lr;
            #pragma unroll
            for (int r = 0; r < 4; ++r) {
                int row = rt * 16 + kg * 4 + r;
                float x = acc[rt][tt][r] + b1r[tt];
                float h = x / (1.0f + __expf(-x));
                int byte = (row * 256 + col * 2) ^ ((row & 7) << 4);
                *(unsigned short*)(hslice + byte) = f2bf(h);
            }
        }

    __syncthreads();   // Wt2e staged

    // ---- GEMM2: K=128, A from private h, B from LDS (barrier-free)
    #pragma unroll
    for (int rt = 0; rt < 2; ++rt)
        #pragma unroll
        for (int tt = 0; tt < 8; ++tt) acc[rt][tt] = (f32x4){0.f, 0.f, 0.f, 0.f};

    #pragma unroll
    for (int q = 0; q < 4; ++q) {
        bf16x8 A2[2];
        #pragma unroll
        for (int rt = 0; rt < 2; ++rt) {
            int row = rt * 16 + lr;
            int byte = (row * 256 + (q * 32 + kg * 8) * 2) ^ ((row & 7) << 4);
            A2[rt] = *(const bf16x8*)(hslice + byte);
        }
        #pragma unroll
        for (int tt = 0; tt < 8; ++tt) {
            int n = tt * 16 + lr;
            bf16x8 B = *(const bf16x8*)(ldsB + n * 256 + (((q * 4 + kg) ^ (n & 7)) << 4));
            #pragma unroll
            for (int rt = 0; rt < 2; ++rt)
                acc[rt][tt] = __builtin_amdgcn_mfma_f32_16x16x32_bf16(A2[rt], B, acc[rt][tt], 0, 0, 0);
        }
    }

    __syncthreads();   // protect ldsB before reuse as f32 staging

    // ---- epilogue 2: f32 re-layout per wave in ldsB slice; coalesced residual+store;
    //      fused dst-segmented aggregation (rows arrive dst-sorted).
    float* sf = (float*)(ldsB + wv * 8448);
    const int c4 = (l & 31) * 4;
    int cur = -1;
    float4 s4 = {0.f, 0.f, 0.f, 0.f};
    #pragma unroll
    for (int rt = 0; rt < 2; ++rt) {
        #pragma unroll
        for (int tt = 0; tt < 8; ++tt) {
            int col = tt * 16 + lr;
            #pragma unroll
            for (int r = 0; r < 4; ++r) {
                int row = kg * 4 + r;
                sf[row * 132 + (col ^ (row & 12))] = acc[rt][tt][r] + b2r[tt];
            }
        }
        #pragma unroll
        for (int ri = 0; ri < 8; ++ri) {
            int row16 = ri * 2 + (l >> 5);
            float4 v = *(const float4*)(sf + row16 * 132 + (c4 ^ (row16 & 12)));
            int gi = eBase + wv * 32 + rt * 16 + row16;
            int e2 = elist[gi];
            int d2 = dsts[gi];
            long gidx = (long)e2 * DIM + c4;
            float4 rsd = *(const float4*)(edge_feat + gidx);
            v.x += rsd.x; v.y += rsd.y; v.z += rsd.z; v.w += rsd.w;
            *(float4*)(out_edge + gidx) = v;
            if (d2 != cur) {
                if (cur >= 0) {
                    float* ap = aggf + (size_t)cur * DIM + c4;
                    atomicAdd(ap + 0, s4.x); atomicAdd(ap + 1, s4.y);
                    atomicAdd(ap + 2, s4.z); atomicAdd(ap + 3, s4.w);
                }
                cur = d2; s4 = v;
            } else {
                s4.x += v.x; s4.y += v.y; s4.z += v.z; s4.w += v.w;
            }
        }
    }
    if (cur >= 0) {
        float* ap = aggf + (size_t)cur * DIM + c4;
        atomicAdd(ap + 0, s4.x); atomicAdd(ap + 1, s4.y);
        atomicAdd(ap + 2, s4.z); atomicAdd(ap + 3, s4.w);
    }
}

// ---------------- node MLP (agg normalized inline from fp32 partials) ----------------
#define SLICE_B 8448
__launch_bounds__(256, 4)
__global__ void node_kernel(const float* __restrict__ node_feat,
                            const unsigned short* __restrict__ node_bf,
                            const float* __restrict__ aggf,
                            const int* __restrict__ counts,
                            const unsigned short* __restrict__ Wt1n,
                            const unsigned short* __restrict__ Wt2n,
                            const float* __restrict__ b1n,
                            const float* __restrict__ b2n,
                            float* __restrict__ out_node) {
    __shared__ char lds[4][SLICE_B];
    const int tid = threadIdx.x;
    const int wv = tid >> 6;
    const int l = tid & 63;
    const int lr = l & 15;
    const int kg = l >> 4;
    char* slice = lds[wv];

    const int nBase = blockIdx.x * 128;
    const int wBase = nBase + wv * 32;

    int rowc[2];
    float inv[2];
    #pragma unroll
    for (int rt = 0; rt < 2; ++rt) {
        int row = wBase + rt * 16 + lr;
        rowc[rt] = row < N_NODES ? row : N_NODES - 1;
        int cnt = counts[rowc[rt]];
        inv[rt] = 1.0f / (float)(cnt > 1 ? cnt : 1);
    }

    f32x4 acc[2][8];
    #pragma unroll
    for (int rt = 0; rt < 2; ++rt)
        #pragma unroll
        for (int t = 0; t < 8; ++t) acc[rt][t] = (f32x4){0.f, 0.f, 0.f, 0.f};

    #pragma unroll
    for (int s = 0; s < 8; ++s) {
        const int kk = s * 32 + kg * 8;
        bf16x8 A[2];
        if (s < 4) {
            #pragma unroll
            for (int rt = 0; rt < 2; ++rt)
                A[rt] = *(const bf16x8*)(node_bf + (long)rowc[rt] * DIM + kk);
        } else {
            #pragma unroll
            for (int rt = 0; rt < 2; ++rt) {
                const float* p = aggf + (size_t)rowc[rt] * DIM + (kk - 128);
                float4 f0 = *(const float4*)p;
                float4 f1 = *(const float4*)(p + 4);
                bf16x8 a;
                a[0] = (short)f2bf(f0.x * inv[rt]); a[1] = (short)f2bf(f0.y * inv[rt]);
                a[2] = (short)f2bf(f0.z * inv[rt]); a[3] = (short)f2bf(f0.w * inv[rt]);
                a[4] = (short)f2bf(f1.x * inv[rt]); a[5] = (short)f2bf(f1.y * inv[rt]);
                a[6] = (short)f2bf(f1.z * inv[rt]); a[7] = (short)f2bf(f1.w * inv[rt]);
                A[rt] = a;
            }
        }
        #pragma unroll
        for (int t = 0; t < 8; ++t) {
            bf16x8 B = *(const bf16x8*)(Wt1n + (t * 16 + lr) * 256 + kk);
            #pragma unroll
            for (int rt = 0; rt < 2; ++rt)
                acc[rt][t] = __builtin_amdgcn_mfma_f32_16x16x32_bf16(A[rt], B, acc[rt][t], 0, 0, 0);
        }
    }

    #pragma unroll
    for (int rt = 0; rt < 2; ++rt) {
        #pragma unroll
        for (int t = 0; t < 8; ++t) {
            float b1 = b1n[t * 16 + lr];
            int col = t * 16 + lr;
            #pragma unroll
            for (int r = 0; r < 4; ++r) {
                int row = rt * 16 + kg * 4 + r;
                float x = acc[rt][t][r] + b1;
                float h = x / (1.0f + __expf(-x));
                int byte = (row * 256 + col * 2) ^ ((row & 7) << 4);
                *(unsigned short*)(slice + byte) = f2bf(h);
            }
        }
    }
    __syncthreads();

    f32x4 acc2[2][8];
    #pragma unroll
    for (int rt = 0; rt < 2; ++rt)
        #pragma unroll
        for (int t = 0; t < 8; ++t) acc2[rt][t] = (f32x4){0.f, 0.f, 0.f, 0.f};

    #pragma unroll
    for (int s = 0; s < 4; ++s) {
        const int kk = s * 32 + kg * 8;
        bf16x8 A[2];
        #pragma unroll
        for (int rt = 0; rt < 2; ++rt) {
            int row = rt * 16 + lr;
            int byte = (row * 256 + kk * 2) ^ ((row & 7) << 4);
            A[rt] = *(const bf16x8*)(slice + byte);
        }
        #pragma unroll
        for (int t = 0; t < 8; ++t) {
            bf16x8 B = *(const bf16x8*)(Wt2n + (t * 16 + lr) * DIM + kk);
            #pragma unroll
            for (int rt = 0; rt < 2; ++rt)
                acc2[rt][t] = __builtin_amdgcn_mfma_f32_16x16x32_bf16(A[rt], B, acc2[rt][t], 0, 0, 0);
        }
    }
    __syncthreads();

    #pragma unroll
    for (int rt = 0; rt < 2; ++rt) {
        float* sf = (float*)slice;
        #pragma unroll
        for (int t = 0; t < 8; ++t) {
            float b2 = b2n[t * 16 + lr];
            int col = t * 16 + lr;
            #pragma unroll
            for (int r = 0; r < 4; ++r) {
                int row = kg * 4 + r;
                int colp = col ^ (row & 12);
                sf[row * 132 + colp] = acc2[rt][t][r] + b2;
            }
        }
        __syncthreads();
        #pragma unroll
        for (int rr = 0; rr < 8; ++rr) {
            int row = rr * 2 + (l >> 5);
            int c4 = (l & 31) * 4;
            int cswz = c4 ^ (row & 12);
            float4 v = *(const float4*)(sf + row * 132 + cswz);
            int grow = wBase + rt * 16 + row;
            if (grow < N_NODES) {
                long gidx = (long)grow * DIM + c4;
                float4 rsd = *(const float4*)(node_feat + gidx);
                v.x += rsd.x; v.y += rsd.y; v.z += rsd.z; v.w += rsd.w;
                *(float4*)(out_node + gidx) = v;
            }
        }
        __syncthreads();
    }
}

extern "C" void kernel_launch(void* const* d_in, const int* in_sizes, int n_in,
                              void* d_out, int out_size, void* d_ws, size_t ws_size,
                              hipStream_t stream) {
    const float* node_feat = (const float*)d_in[0];
    const float* edge_feat = (const float*)d_in[1];
    const int*   eidx      = (const int*)d_in[2];
    const float* W1e = (const float*)d_in[3];
    const float* b1e = (const float*)d_in[4];
    const float* W2e = (const float*)d_in[5];
    const float* b2e = (const float*)d_in[6];
    const float* W1n = (const float*)d_in[7];
    const float* b1n = (const float*)d_in[8];
    const float* W2n = (const float*)d_in[9];
    const float* b2n = (const float*)d_in[10];

    char* ws = (char*)d_ws;
    size_t off = 0;
    auto alloc = [&](size_t bytes) {
        void* p = ws + off;
        off += (bytes + 255) & ~(size_t)255;
        return p;
    };
    unsigned short* node_bf = (unsigned short*)alloc((size_t)N_NODES * DIM * 2);
    float*          aggf    = (float*)alloc((size_t)N_NODES * DIM * 4);
    unsigned short* Wt1e    = (unsigned short*)alloc((size_t)DIM * 384 * 2);
    unsigned short* Wt2e    = (unsigned short*)alloc((size_t)DIM * DIM * 2);
    unsigned short* Wt1n    = (unsigned short*)alloc((size_t)DIM * 256 * 2);
    unsigned short* Wt2n    = (unsigned short*)alloc((size_t)DIM * DIM * 2);
    int* counts  = (int*)alloc((size_t)N_NODES * 4);
    int* offsets = (int*)alloc((size_t)N_NODES * 4);
    int* cursor  = (int*)alloc((size_t)N_NODES * 4);
    int* elist   = (int*)alloc((size_t)N_EDGES * 4);
    int* dsts    = (int*)alloc((size_t)N_EDGES * 4);

    float* out_node = (float*)d_out;
    float* out_edge = out_node + (size_t)N_NODES * DIM;

    prep_kernel<<<512, 256, 0, stream>>>(node_feat, W1e, W2e, W1n, W2n,
                                         node_bf, Wt1e, Wt2e, Wt1n, Wt2n, counts, aggf);
    count_kernel<<<(N_EDGES + 255) / 256, 256, 0, stream>>>(eidx, counts);
    scan_kernel<<<1, 1024, 0, stream>>>(counts, offsets, cursor);
    scatter_kernel<<<(N_EDGES + 255) / 256, 256, 0, stream>>>(eidx, cursor, elist, dsts);
    edge_kernel<<<N_EDGES / 128, 256, 0, stream>>>(edge_feat, eidx, elist, dsts, node_bf,
                                                   Wt1e, Wt2e, b1e, b2e, out_edge, aggf);
    node_kernel<<<(N_NODES + 127) / 128, 256, 0, stream>>>(node_feat, node_bf, aggf, counts,
                                                           Wt1n, Wt2n, b1n, b2n, out_node);
}